// Round 1
// baseline (119.440 us; speedup 1.0000x reference)
//
#include <hip/hip_runtime.h>

// Problem dims
constexpr int N_   = 256;
constexpr int T_   = 2048;
constexpr int V_   = 9;
constexpr int CIN_ = 16;
constexpr int COUT_= 3;
constexpr int K_   = 5;
constexpr int KT_  = 9;
constexpr int FIN_ = V_ * CIN_;   // 144
constexpr int J_   = V_ * COUT_;  // 27 (j = w*3 + o)
constexpr int THREADS_ = 256;
constexpr int TILE_ = THREADS_ - (KT_ - 1);          // 248 output rows per block
constexpr int NTILE_ = (T_ + TILE_ - 1) / TILE_;     // 9
constexpr int ZS_ = 28;                              // padded z row stride (floats)

// ws layout (floats)
constexpr int WC_OFF = 0;               // Wc[f][j], 144*27 = 3888
constexpr int B0_OFF = FIN_ * J_;       // 3888, B0[j], 27
constexpr int WT_OFF = B0_OFF + J_;     // 3915, Wt[o][o2][dd], 81
constexpr int BT_OFF = WT_OFF + 81;     // 3996, b_tcn, 3
// total 3999 floats

__global__ void setup_weights(const float* __restrict__ A,
                              const float* __restrict__ Wg,
                              const float* __restrict__ bg,
                              const float* __restrict__ Wt_in,
                              const float* __restrict__ bt,
                              float* __restrict__ ws) {
    const int tid = threadIdx.x;
    // Wc[f=(v*16+c)][j=(w*3+o)] = sum_k Wg[k,o,c] * A[k,v,w]
    for (int idx = tid; idx < FIN_ * J_; idx += blockDim.x) {
        const int f = idx / J_, j = idx % J_;
        const int v = f >> 4, c = f & 15;
        const int w = j / 3, o = j % 3;
        float s = 0.f;
        #pragma unroll
        for (int k = 0; k < K_; ++k)
            s += Wg[(k * 3 + o) * 16 + c] * A[(k * 9 + v) * 9 + w];
        ws[WC_OFF + idx] = s;
    }
    // B0[j] = sum_k bg[k,o] * sum_v A[k,v,w]
    if (tid < J_) {
        const int w = tid / 3, o = tid % 3;
        float s = 0.f;
        #pragma unroll
        for (int k = 0; k < K_; ++k) {
            float cs = 0.f;
            #pragma unroll
            for (int v = 0; v < V_; ++v) cs += A[(k * 9 + v) * 9 + w];
            s += bg[k * 3 + o] * cs;
        }
        ws[B0_OFF + tid] = s;
    }
    // Wt[o][o2][dd] = W_tcn[(o2*3 + o)*9 + (8 - dd)]
    // (jax conv_transpose, transpose_kernel=True: flip kt, swap I/O channel dims)
    if (tid < 81) {
        const int o = tid / 27, r = tid % 27, o2 = r / 9, dd = r % 9;
        ws[WT_OFF + tid] = Wt_in[(o2 * 3 + o) * 9 + (8 - dd)];
    }
    if (tid < 3) ws[BT_OFF + tid] = bt[tid];
}

__global__ __launch_bounds__(THREADS_) void fused_stgcn(const float* __restrict__ pose,
                                                        const float* __restrict__ cw,
                                                        float* __restrict__ out) {
    __shared__ float zbuf[THREADS_ * ZS_];  // 28672 B

    const int tid  = threadIdx.x;
    const int bid  = blockIdx.x;
    const int n    = bid / NTILE_;
    const int tile = bid % NTILE_;
    const int t0   = tile * TILE_;

    // ---------------- Stage 1: z[text] = pose_row(144) x Wc(144x27) + B0 ----------------
    float acc[J_];
    const int text = t0 - 4 + tid;   // extended row (halo of 4 each side)
    if (text >= 0 && text < T_) {
        #pragma unroll
        for (int j = 0; j < J_; ++j) acc[j] = cw[B0_OFF + j];
        const float4* row4 = (const float4*)(pose + ((size_t)n * T_ + text) * FIN_);
        float4 nx0 = row4[0], nx1 = row4[1], nx2 = row4[2], nx3 = row4[3];
        #pragma unroll 1
        for (int v9 = 0; v9 < V_; ++v9) {
            const float4 x0 = nx0, x1 = nx1, x2 = nx2, x3 = nx3;
            if (v9 < V_ - 1) {
                nx0 = row4[(v9 + 1) * 4 + 0];
                nx1 = row4[(v9 + 1) * 4 + 1];
                nx2 = row4[(v9 + 1) * 4 + 2];
                nx3 = row4[(v9 + 1) * 4 + 3];
            }
            float xs[16];
            xs[0]=x0.x; xs[1]=x0.y; xs[2]=x0.z; xs[3]=x0.w;
            xs[4]=x1.x; xs[5]=x1.y; xs[6]=x1.z; xs[7]=x1.w;
            xs[8]=x2.x; xs[9]=x2.y; xs[10]=x2.z; xs[11]=x2.w;
            xs[12]=x3.x; xs[13]=x3.y; xs[14]=x3.z; xs[15]=x3.w;
            const float* wrow = cw + WC_OFF + (v9 * 16) * J_;
            #pragma unroll
            for (int c = 0; c < 16; ++c) {
                const float xv = xs[c];
                #pragma unroll
                for (int j = 0; j < J_; ++j)
                    acc[j] = fmaf(xv, wrow[c * J_ + j], acc[j]);
            }
        }
    } else {
        #pragma unroll
        for (int j = 0; j < J_; ++j) acc[j] = 0.f;
    }
    #pragma unroll
    for (int j = 0; j < J_; ++j) zbuf[tid * ZS_ + j] = acc[j];
    __syncthreads();

    // ---------------- Stage 2: temporal 9-tap mix + bias + leaky relu ----------------
    const int rows_out = min(TILE_, T_ - t0);
    float oacc[J_];
    if (tid < rows_out) {
        #pragma unroll
        for (int w = 0; w < V_; ++w)
            #pragma unroll
            for (int o2 = 0; o2 < 3; ++o2)
                oacc[w * 3 + o2] = cw[BT_OFF + o2];
        #pragma unroll
        for (int dd = 0; dd < KT_; ++dd) {
            float zr[J_];
            const float* zp = &zbuf[(tid + dd) * ZS_];
            #pragma unroll
            for (int j = 0; j < J_; ++j) zr[j] = zp[j];
            #pragma unroll
            for (int o = 0; o < 3; ++o) {
                #pragma unroll
                for (int o2 = 0; o2 < 3; ++o2) {
                    const float wv = cw[WT_OFF + o * 27 + o2 * 9 + dd];
                    #pragma unroll
                    for (int w = 0; w < V_; ++w)
                        oacc[w * 3 + o2] = fmaf(zr[w * 3 + o], wv, oacc[w * 3 + o2]);
                }
            }
        }
        #pragma unroll
        for (int j = 0; j < J_; ++j) oacc[j] = fmaxf(oacc[j], 0.01f * oacc[j]);
    }
    __syncthreads();
    // repack results tightly (stride 27) for coalesced copy-out
    if (tid < rows_out) {
        #pragma unroll
        for (int j = 0; j < J_; ++j) zbuf[tid * J_ + j] = oacc[j];
    }
    __syncthreads();

    const int total4 = (rows_out * J_) / 4;  // 248*27 and 64*27 both %4==0
    float4* dst4 = (float4*)(out + ((size_t)n * T_ + t0) * J_);
    const float4* src4 = (const float4*)zbuf;
    for (int idx = tid; idx < total4; idx += THREADS_)
        dst4[idx] = src4[idx];
}

extern "C" void kernel_launch(void* const* d_in, const int* in_sizes, int n_in,
                              void* d_out, int out_size, void* d_ws, size_t ws_size,
                              hipStream_t stream) {
    const float* pose = (const float*)d_in[0];
    const float* A    = (const float*)d_in[1];
    const float* Wg   = (const float*)d_in[2];
    const float* bg   = (const float*)d_in[3];
    const float* Wt   = (const float*)d_in[4];
    const float* bt   = (const float*)d_in[5];
    float* ws  = (float*)d_ws;
    float* outp = (float*)d_out;

    setup_weights<<<1, 256, 0, stream>>>(A, Wg, bg, Wt, bt, ws);
    fused_stgcn<<<N_ * NTILE_, THREADS_, 0, stream>>>(pose, ws, outp);
}